// Round 1
// baseline (329.527 us; speedup 1.0000x reference)
//
#include <hip/hip_runtime.h>
#include <stdint.h>

// CIN forward, MI355X. Per batch b: Z(128x64) = W(128xK) @ P(Kx64),
// P[c*32+m, d] = h[c,d]*x[m,d], fused into MFMA B-frag generation.
// 512 blocks x 256 threads; 2 batches/block (W frags reused in-register);
// mfma_f32_16x16x32_bf16; h ping-pongs through padded LDS (transposed).

typedef __attribute__((ext_vector_type(8))) __bf16 bf16x8;
typedef __attribute__((ext_vector_type(4))) float f32x4;
typedef __attribute__((ext_vector_type(4))) int i32x4;

union AB {
  i32x4 i;
  bf16x8 b;
  uint32_t u[4];
};

static __device__ __forceinline__ float bflo_to_f(uint32_t lo16) {
  return __builtin_bit_cast(float, lo16 << 16);
}
static __device__ __forceinline__ uint32_t pk_bf16(float a, float b) {
  // gfx950: two fptrunc-to-bf16 fuse to v_cvt_pk_bf16_f32
  uint16_t ux = __builtin_bit_cast(uint16_t, (__bf16)a);
  uint16_t uy = __builtin_bit_cast(uint16_t, (__bf16)b);
  return (uint32_t)ux | ((uint32_t)uy << 16);
}
static __device__ __forceinline__ uint16_t f_to_bf16(float a) {
  return __builtin_bit_cast(uint16_t, (__bf16)a);
}

#define HPAD 136  // 128 channels + 8 pad: row stride 272B -> 2-way LDS aliasing only (free)

__global__ __launch_bounds__(256, 2) void cin_main(
    const float* __restrict__ x, const uint16_t* __restrict__ wp,
    const float* __restrict__ bias0, const float* __restrict__ bias1,
    const float* __restrict__ bias2, float* __restrict__ out) {
  __shared__ __align__(16) uint16_t hT[2][2][64][HPAD];  // [buf][batch][d][chan]

  const int tid = threadIdx.x;
  const int w = tid >> 6;       // wave 0..3 -> o-rows [32w, 32w+32)
  const int lane = tid & 63;
  const int q = lane >> 4;      // quad: k = q*8+j in frags; row o = q*4+r in C
  const int i = lane & 15;      // col d (mod 16) in B/C; row o (mod 16) in A
  const int bb = blockIdx.x * 2;

  // ---- stage x -> hT[0][p][d][c] as bf16 (layer-0 h == x, 32 channels)
  for (int e = tid; e < 4096; e += 256) {
    int p = e >> 11, c = (e >> 6) & 31, d = e & 63;
    hT[0][p][d][c] = f_to_bf16(x[(size_t)(bb + p) * 2048 + c * 64 + d]);
  }
  __syncthreads();

  // ---- x fragments (B-operand layout), loop-invariant across all layers.
  // xf[p][t][j] = f32(bf16(x[b_p, m=q*8+j, d=t*16+i]))
  float xf[2][4][8];
#pragma unroll
  for (int p = 0; p < 2; ++p)
#pragma unroll
    for (int t = 0; t < 4; ++t) {
      const uint16_t* hp = &hT[0][p][t * 16 + i][q * 8];
      uint4 raw = *(const uint4*)hp;  // ds_read_b128 (16B aligned: 272*d + 16*q)
      uint32_t wd[4] = {raw.x, raw.y, raw.z, raw.w};
#pragma unroll
      for (int k = 0; k < 4; ++k) {
        xf[p][t][2 * k] = bflo_to_f(wd[k] & 0xffffu);
        xf[p][t][2 * k + 1] = __builtin_bit_cast(float, wd[k] & 0xffff0000u);
      }
    }

#pragma unroll 1
  for (int L = 0; L < 3; ++L) {
    const int Kch = (L == 0) ? 32 : 128;  // input channels this layer
    const uint16_t* W = (L == 0) ? wp : (L == 1) ? wp + 131072 : wp + 131072 + 524288;
    const float* bias = (L == 0) ? bias0 : (L == 1) ? bias1 : bias2;
    const int rb = (L == 1) ? 1 : 0;  // read buffer: 0,1,0
    const int wb = 1 - rb;

    // packed W: elem offset ((otile*Kch + c)*64 + lane)*8 -> coalesced 1KB/frag
    const uint16_t* wA0 = W + (size_t)(2 * w) * Kch * 512 + lane * 8;
    const uint16_t* wA1 = W + (size_t)(2 * w + 1) * Kch * 512 + lane * 8;

    f32x4 acc[2][2][4];  // [batch][otile][dtile]
#pragma unroll
    for (int p = 0; p < 2; ++p)
#pragma unroll
      for (int g = 0; g < 2; ++g)
#pragma unroll
        for (int t = 0; t < 4; ++t) acc[p][g][t] = (f32x4){0.f, 0.f, 0.f, 0.f};

#pragma unroll 1
    for (int c0 = 0; c0 < Kch; c0 += 4) {
      // h scalars for 4 channels: hT[rb][p][d=t*16+i][c0..c0+3]  (ds_read_b64)
      uint2 hv[2][4];
#pragma unroll
      for (int p = 0; p < 2; ++p)
#pragma unroll
        for (int t = 0; t < 4; ++t)
          hv[p][t] = *(const uint2*)&hT[rb][p][t * 16 + i][c0];

      // W frags for 4 channels x 2 o-tiles (global_load_dwordx4, L2-resident)
      AB aw[4][2];
#pragma unroll
      for (int cc = 0; cc < 4; ++cc) {
        aw[cc][0].i = *(const i32x4*)(wA0 + (size_t)(c0 + cc) * 512);
        aw[cc][1].i = *(const i32x4*)(wA1 + (size_t)(c0 + cc) * 512);
      }

#pragma unroll
      for (int cc = 0; cc < 4; ++cc) {
        bf16x8 af0 = aw[cc][0].b;
        bf16x8 af1 = aw[cc][1].b;
#pragma unroll
        for (int p = 0; p < 2; ++p)
#pragma unroll
          for (int t = 0; t < 4; ++t) {
            uint32_t word = (cc < 2) ? hv[p][t].x : hv[p][t].y;
            float hs = (cc & 1) ? __builtin_bit_cast(float, word & 0xffff0000u)
                                : bflo_to_f(word & 0xffffu);
            AB bfr;  // B-frag: P[c*32 + q*8+j][d] = h[c,d] * x[q*8+j,d]
#pragma unroll
            for (int k = 0; k < 4; ++k)
              bfr.u[k] = pk_bf16(hs * xf[p][t][2 * k], hs * xf[p][t][2 * k + 1]);
            acc[p][0][t] = __builtin_amdgcn_mfma_f32_16x16x32_bf16(af0, bfr.b, acc[p][0][t], 0, 0, 0);
            acc[p][1][t] = __builtin_amdgcn_mfma_f32_16x16x32_bf16(af1, bfr.b, acc[p][1][t], 0, 0, 0);
          }
      }
    }

    // ---- epilogue: bias + ReLU (C layout: o = (2w+g)*16 + q*4 + r, d = t*16 + i)
    f32x4 bv[2];
#pragma unroll
    for (int g = 0; g < 2; ++g)
      bv[g] = *(const f32x4*)(bias + (2 * w + g) * 16 + q * 4);
#pragma unroll
    for (int p = 0; p < 2; ++p)
#pragma unroll
      for (int g = 0; g < 2; ++g)
#pragma unroll
        for (int t = 0; t < 4; ++t)
#pragma unroll
          for (int r = 0; r < 4; ++r)
            acc[p][g][t][r] = fmaxf(acc[p][g][t][r] + bv[g][r], 0.f);

    // next-layer h -> LDS (transposed, bf16), skip after last layer
    if (L < 2) {
#pragma unroll
      for (int p = 0; p < 2; ++p)
#pragma unroll
        for (int g = 0; g < 2; ++g)
#pragma unroll
          for (int t = 0; t < 4; ++t) {
            uint2 pkd;
            pkd.x = pk_bf16(acc[p][g][t][0], acc[p][g][t][1]);
            pkd.y = pk_bf16(acc[p][g][t][2], acc[p][g][t][3]);
            *(uint2*)&hT[wb][p][t * 16 + i][(2 * w + g) * 16 + q * 4] = pkd;
          }
    }

    // d-sum: per-lane over 4 d-tiles, then xor-reduce the 16 lanes of the quad
#pragma unroll
    for (int p = 0; p < 2; ++p)
#pragma unroll
      for (int g = 0; g < 2; ++g)
#pragma unroll
        for (int r = 0; r < 4; ++r) {
          float s = acc[p][g][0][r] + acc[p][g][1][r] + acc[p][g][2][r] + acc[p][g][3][r];
          s += __shfl_xor(s, 1);
          s += __shfl_xor(s, 2);
          s += __shfl_xor(s, 4);
          s += __shfl_xor(s, 8);
          if (i == 0)
            out[(size_t)(bb + p) * 384 + L * 128 + (2 * w + g) * 16 + q * 4 + r] = s;
        }

    if (L < 2) __syncthreads();  // ping-pong: one barrier per layer suffices
  }
}

// Pre-pass: W fp32 -> bf16, fragment-major [otile][c][lane][j] so the main
// kernel's per-frag load is one contiguous, coalesced 1KB dwordx4 per wave.
__global__ void pack_w(const float* __restrict__ W, uint16_t* __restrict__ Wp,
                       int kshift) {
  const int Kch = 1 << kshift;
  int idx = blockIdx.x * 256 + threadIdx.x;   // ((ot*Kch + c)*4 + q)*16 + i
  int lane = idx & 63;
  int qq = lane >> 4, ii = lane & 15;
  int rest = idx >> 6;
  int c = rest & (Kch - 1);
  int ot = rest >> kshift;
  const float* src = W + (size_t)(ot * 16 + ii) * (Kch * 32) + c * 32 + qq * 8;
  uint32_t o[4];
#pragma unroll
  for (int k = 0; k < 4; ++k) o[k] = pk_bf16(src[2 * k], src[2 * k + 1]);
  uint4 val;
  val.x = o[0]; val.y = o[1]; val.z = o[2]; val.w = o[3];
  *(uint4*)(Wp + (size_t)idx * 8) = val;
}

extern "C" void kernel_launch(void* const* d_in, const int* in_sizes, int n_in,
                              void* d_out, int out_size, void* d_ws, size_t ws_size,
                              hipStream_t stream) {
  (void)in_sizes; (void)n_in; (void)out_size; (void)ws_size;
  const float* x  = (const float*)d_in[0];
  const float* W0 = (const float*)d_in[1];
  const float* b0 = (const float*)d_in[2];
  const float* W1 = (const float*)d_in[3];
  const float* b1 = (const float*)d_in[4];
  const float* W2 = (const float*)d_in[5];
  const float* b2 = (const float*)d_in[6];
  uint16_t* wpacked = (uint16_t*)d_ws;  // 2.25 MB of ws used

  hipLaunchKernelGGL(pack_w, dim3(64),  dim3(256), 0, stream, W0, wpacked, 5);
  hipLaunchKernelGGL(pack_w, dim3(256), dim3(256), 0, stream, W1, wpacked + 131072, 7);
  hipLaunchKernelGGL(pack_w, dim3(256), dim3(256), 0, stream, W2, wpacked + 131072 + 524288, 7);
  hipLaunchKernelGGL(cin_main, dim3(512), dim3(256), 0, stream,
                     x, wpacked, b0, b1, b2, (float*)d_out);
}

// Round 2
// 233.801 us; speedup vs baseline: 1.4094x; 1.4094x over previous
//
#include <hip/hip_runtime.h>
#include <stdint.h>

// CIN forward, MI355X. Per batch b: Z(128x64) = W(128xK) @ P(Kx64),
// P[c*32+m, d] = h[c,d]*x[m,d], fused into MFMA B-frag generation.
// R2 repartition: 4 waves = 2 batches x 2 d-halves (t in {2th, 2th+1}).
// Each wave computes ALL 8 o-tiles per B-frag -> frag build amortized over
// 8 MFMAs, zero cross-wave duplication (was 4x in R1, VALUBusy 80%).

typedef __attribute__((ext_vector_type(8))) __bf16 bf16x8;
typedef __attribute__((ext_vector_type(2))) __bf16 bf16x2;
typedef __attribute__((ext_vector_type(4))) float f32x4;
typedef __attribute__((ext_vector_type(4))) int i32x4;

union AB {
  i32x4 i;
  bf16x8 b;
  uint32_t u[4];
};

static __device__ __forceinline__ float bflo_to_f(uint32_t lo16) {
  return __builtin_bit_cast(float, lo16 << 16);
}
static __device__ __forceinline__ uint32_t pk_bf16(float a, float b) {
#if __has_builtin(__builtin_amdgcn_cvt_pk_bf16_f32)
  bf16x2 v = __builtin_amdgcn_cvt_pk_bf16_f32(a, b);
  return __builtin_bit_cast(uint32_t, v);
#else
  uint16_t ux = __builtin_bit_cast(uint16_t, (__bf16)a);
  uint16_t uy = __builtin_bit_cast(uint16_t, (__bf16)b);
  return (uint32_t)ux | ((uint32_t)uy << 16);
#endif
}
static __device__ __forceinline__ uint16_t f_to_bf16(float a) {
  return __builtin_bit_cast(uint16_t, (__bf16)a);
}

#define HPAD 136  // row stride 272B: 16B-aligned for b128, stride-272 reads are 2-way (free)

__global__ __launch_bounds__(256, 2) void cin_main(
    const float* __restrict__ x, const uint16_t* __restrict__ wp,
    const float* __restrict__ bias0, const float* __restrict__ bias1,
    const float* __restrict__ bias2, float* __restrict__ out) {
  __shared__ __align__(16) uint16_t hT[2][2][64][HPAD];  // [buf][batch][d][chan]
  __shared__ float sOut[2][2][2][128];                   // [L&1][batch][thalf][o]

  const int tid = threadIdx.x;
  const int w = tid >> 6;
  const int lane = tid & 63;
  const int q = lane >> 4;   // quad: k = q*8+j in frags; row o = q*4+r in C
  const int i = lane & 15;   // col d (mod 16) in B/C; row o (mod 16) in A
  const int p = w >> 1;      // batch within block (0/1)
  const int th = w & 1;      // d-half: this wave owns t = 2*th + u, u in {0,1}
  const int bb = blockIdx.x * 2;

  // ---- stage x -> hT[0][p][d][c] as bf16 (layer-0 h == x, 32 channels)
  for (int e = tid; e < 4096; e += 256) {
    int pp = e >> 11, c = (e >> 6) & 31, d = e & 63;
    hT[0][pp][d][c] = f_to_bf16(x[(size_t)(bb + pp) * 2048 + c * 64 + d]);
  }
  __syncthreads();

  // ---- x fragments (B-operand layout), loop-invariant across all layers.
  // xf[u][j] = f32(bf16(x[b_p, m=q*8+j, d=(2*th+u)*16+i]))
  float xf[2][8];
#pragma unroll
  for (int u = 0; u < 2; ++u) {
    const uint16_t* hp = &hT[0][p][(2 * th + u) * 16 + i][q * 8];
    uint4 raw = *(const uint4*)hp;  // ds_read_b128 (272*d + 16*q: 16B aligned)
    uint32_t wd[4] = {raw.x, raw.y, raw.z, raw.w};
#pragma unroll
    for (int k = 0; k < 4; ++k) {
      xf[u][2 * k] = bflo_to_f(wd[k] & 0xffffu);
      xf[u][2 * k + 1] = __builtin_bit_cast(float, wd[k] & 0xffff0000u);
    }
  }

#pragma unroll
  for (int L = 0; L < 3; ++L) {
    const int Kch = (L == 0) ? 32 : 128;  // input channels this layer
    const uint16_t* W = (L == 0) ? wp : (L == 1) ? wp + 131072 : wp + 131072 + 524288;
    const float* bias = (L == 0) ? bias0 : (L == 1) ? bias1 : bias2;
    const int rb = (L == 1) ? 1 : 0;  // ping-pong read buffer: 0,1,0
    const int wb = 1 - rb;

    const uint16_t* wBase = W + lane * 8;  // frag elem off: ((ot*Kch + c)*64 + lane)*8

    f32x4 acc[8][2];  // [otile][u]; 32 independent accumulator chains
#pragma unroll
    for (int ot = 0; ot < 8; ++ot)
#pragma unroll
      for (int u = 0; u < 2; ++u) acc[ot][u] = (f32x4){0.f, 0.f, 0.f, 0.f};

#pragma unroll 1
    for (int c0 = 0; c0 < Kch; c0 += 2) {
      // h for 2 channels, both d-tiles of this wave's half (ds_read_b32 x2)
      uint32_t hv[2];
#pragma unroll
      for (int u = 0; u < 2; ++u)
        hv[u] = *(const uint32_t*)&hT[rb][p][(2 * th + u) * 16 + i][c0];

      // W frags: 2 channels x 8 o-tiles (global_load_dwordx4; L1/L2-resident,
      // same lines read by all 4 waves of the block -> L1 serves the reuse)
      AB aw[2][8];
#pragma unroll
      for (int cc = 0; cc < 2; ++cc)
#pragma unroll
        for (int ot = 0; ot < 8; ++ot)
          aw[cc][ot].i = *(const i32x4*)(wBase + ((size_t)(ot * Kch + c0 + cc) << 9));

#pragma unroll
      for (int cc = 0; cc < 2; ++cc)
#pragma unroll
        for (int u = 0; u < 2; ++u) {
          float hs = cc ? __builtin_bit_cast(float, hv[u] & 0xffff0000u)
                        : __builtin_bit_cast(float, hv[u] << 16);
          AB bfr;  // B-frag: P[c*32 + q*8+j][d] = h[c,d] * x[q*8+j,d]
#pragma unroll
          for (int k = 0; k < 4; ++k)
            bfr.u[k] = pk_bf16(hs * xf[u][2 * k], hs * xf[u][2 * k + 1]);
#pragma unroll
          for (int ot = 0; ot < 8; ++ot)
            acc[ot][u] = __builtin_amdgcn_mfma_f32_16x16x32_bf16(
                aw[cc][ot].b, bfr.b, acc[ot][u], 0, 0, 0);
        }
    }

    // ---- epilogue: bias + ReLU (C layout: o = ot*16 + q*4 + r, d = (2th+u)*16 + i)
#pragma unroll
    for (int ot = 0; ot < 8; ++ot) {
      f32x4 bv = *(const f32x4*)(bias + ot * 16 + q * 4);
#pragma unroll
      for (int u = 0; u < 2; ++u)
#pragma unroll
        for (int r = 0; r < 4; ++r)
          acc[ot][u][r] = fmaxf(acc[ot][u][r] + bv[r], 0.f);
    }

    // next-layer h -> LDS (transposed bf16); disjoint d-rows per wave
    if (L < 2) {
#pragma unroll
      for (int ot = 0; ot < 8; ++ot)
#pragma unroll
        for (int u = 0; u < 2; ++u) {
          uint2 pkd;
          pkd.x = pk_bf16(acc[ot][u][0], acc[ot][u][1]);
          pkd.y = pk_bf16(acc[ot][u][2], acc[ot][u][3]);
          *(uint2*)&hT[wb][p][(2 * th + u) * 16 + i][ot * 16 + q * 4] = pkd;
        }
    }

    // d-partials: sum this wave's 2 d-tiles, xor-reduce the 16 i-lanes
#pragma unroll
    for (int ot = 0; ot < 8; ++ot)
#pragma unroll
      for (int r = 0; r < 4; ++r) {
        float s = acc[ot][0][r] + acc[ot][1][r];
        s += __shfl_xor(s, 1);
        s += __shfl_xor(s, 2);
        s += __shfl_xor(s, 4);
        s += __shfl_xor(s, 8);
        if (i == 0) sOut[L & 1][p][th][ot * 16 + q * 4 + r] = s;
      }

    __syncthreads();  // covers hT ping-pong AND sOut partials

    // combine the two d-halves, write out (coalesced, 256 lanes = 2b x 128o)
    {
      int b2 = tid >> 7, o = tid & 127;
      out[(size_t)(bb + b2) * 384 + L * 128 + o] =
          sOut[L & 1][b2][0][o] + sOut[L & 1][b2][1][o];
    }
    // sOut double-buffers on L&1; a barrier always separates reuse of a slot.
  }
}

// Pre-pass: W fp32 -> bf16, fragment-major [otile][c][lane][j] so the main
// kernel's per-frag load is one contiguous, coalesced 1KB dwordx4 per wave.
__global__ void pack_w(const float* __restrict__ W, uint16_t* __restrict__ Wp,
                       int kshift) {
  const int Kch = 1 << kshift;
  int idx = blockIdx.x * 256 + threadIdx.x;   // ((ot*Kch + c)*4 + q)*16 + i
  int lane = idx & 63;
  int qq = lane >> 4, ii = lane & 15;
  int rest = idx >> 6;
  int c = rest & (Kch - 1);
  int ot = rest >> kshift;
  const float* src = W + (size_t)(ot * 16 + ii) * (Kch * 32) + c * 32 + qq * 8;
  uint32_t o[4];
#pragma unroll
  for (int k = 0; k < 4; ++k) o[k] = pk_bf16(src[2 * k], src[2 * k + 1]);
  uint4 val;
  val.x = o[0]; val.y = o[1]; val.z = o[2]; val.w = o[3];
  *(uint4*)(Wp + (size_t)idx * 8) = val;
}

extern "C" void kernel_launch(void* const* d_in, const int* in_sizes, int n_in,
                              void* d_out, int out_size, void* d_ws, size_t ws_size,
                              hipStream_t stream) {
  (void)in_sizes; (void)n_in; (void)out_size; (void)ws_size;
  const float* x  = (const float*)d_in[0];
  const float* W0 = (const float*)d_in[1];
  const float* b0 = (const float*)d_in[2];
  const float* W1 = (const float*)d_in[3];
  const float* b1 = (const float*)d_in[4];
  const float* W2 = (const float*)d_in[5];
  const float* b2 = (const float*)d_in[6];
  uint16_t* wpacked = (uint16_t*)d_ws;  // 2.25 MB of ws used

  hipLaunchKernelGGL(pack_w, dim3(64),  dim3(256), 0, stream, W0, wpacked, 5);
  hipLaunchKernelGGL(pack_w, dim3(256), dim3(256), 0, stream, W1, wpacked + 131072, 7);
  hipLaunchKernelGGL(pack_w, dim3(256), dim3(256), 0, stream, W2, wpacked + 131072 + 524288, 7);
  hipLaunchKernelGGL(cin_main, dim3(512), dim3(256), 0, stream,
                     x, wpacked, b0, b1, b2, (float*)d_out);
}

// Round 3
// 203.288 us; speedup vs baseline: 1.6210x; 1.1501x over previous
//
#include <hip/hip_runtime.h>
#include <stdint.h>

// CIN forward, MI355X. R3: fp16 MFMA, 1 batch/block (grid 1024, 4 blocks/CU,
// 4 waves/SIMD), wave = (ot-pair x all 4 d-tiles): W-frag reuse R=4.
// h stored in LDS as DUPLICATED fp16 pairs -> ds_read_b64 gives ready
// v_pk_mul_f16 operands (zero splat cost). 1-channel W-frag prefetch.

typedef __attribute__((ext_vector_type(8))) _Float16 f16x8;
typedef __attribute__((ext_vector_type(4))) float f32x4;
typedef __attribute__((ext_vector_type(4))) int i32x4;

union AB {
  i32x4 i;
  f16x8 h;
  uint32_t u[4];
};

static __device__ __forceinline__ uint16_t f_to_f16u(float a) {
  return __builtin_bit_cast(uint16_t, (_Float16)a);
}
static __device__ __forceinline__ uint32_t dup16(uint16_t u) {
  return (uint32_t)u | ((uint32_t)u << 16);
}

#define HP 132  // hD row stride in dwords: 128 ch + 4 pad (16B-aligned rows, 2-way banks)

__global__ __launch_bounds__(256, 4) void cin_main(
    const float* __restrict__ x, const uint16_t* __restrict__ wp,
    const float* __restrict__ bias0, const float* __restrict__ bias1,
    const float* __restrict__ bias2, float* __restrict__ out) {
  __shared__ __align__(16) uint32_t hD[64][HP];  // [d][c]: (f16,f16) duplicated pairs

  const int tid = threadIdx.x;
  const int w = tid >> 6, lane = tid & 63;
  const int q = lane >> 4, i = lane & 15;
  const int b = blockIdx.x;

  // ---- stage x -> hD[d][m] = dup(f16(x[b,m,d]))  (layer-0 h == x)
  for (int e = tid; e < 2048; e += 256) {
    int m = e >> 6, d = e & 63;
    hD[d][m] = dup16(f_to_f16u(x[(size_t)b * 2048 + e]));
  }
  __syncthreads();

  // ---- x fragments (B-operand layout), loop-invariant across layers.
  // xf[t] = f16x8 of x[m=q*8+j][d=t*16+i], packed from dup'd dwords via v_perm.
  AB xf[4];
#pragma unroll
  for (int t = 0; t < 4; ++t) {
    const uint32_t* p = &hD[t * 16 + i][q * 8];
    uint4 r0 = *(const uint4*)p;       // ds_read_b128 (dword off 132*d+8q = 0 mod 4)
    uint4 r1 = *(const uint4*)(p + 4);
    xf[t].u[0] = __builtin_amdgcn_perm(r0.y, r0.x, 0x05040100u);  // lo16s packed
    xf[t].u[1] = __builtin_amdgcn_perm(r0.w, r0.z, 0x05040100u);
    xf[t].u[2] = __builtin_amdgcn_perm(r1.y, r1.x, 0x05040100u);
    xf[t].u[3] = __builtin_amdgcn_perm(r1.w, r1.z, 0x05040100u);
  }

#pragma unroll
  for (int L = 0; L < 3; ++L) {
    const int Kch = (L == 0) ? 32 : 128;
    const uint16_t* W = (L == 0) ? wp : (L == 1) ? wp + 131072 : wp + 131072 + 524288;
    const float* bias = (L == 0) ? bias0 : (L == 1) ? bias1 : bias2;

    // packed W frag elem offset: ((ot*Kch + c)*64 + lane)*8 ; wave owns ot=2w,2w+1
    const uint16_t* wB0 = W + ((size_t)(2 * w) * Kch) * 512 + lane * 8;
    const uint16_t* wB1 = W + ((size_t)(2 * w + 1) * Kch) * 512 + lane * 8;

    f32x4 acc[4][2];  // [t][g]
#pragma unroll
    for (int t = 0; t < 4; ++t)
#pragma unroll
      for (int g = 0; g < 2; ++g) acc[t][g] = (f32x4){0.f, 0.f, 0.f, 0.f};

    AB a0[2], a1[2];
    a0[0].i = *(const i32x4*)(wB0);  // c=0 prologue
    a0[1].i = *(const i32x4*)(wB1);

#pragma unroll 1
    for (int c0 = 0; c0 < Kch; c0 += 2) {
      // W frags for channel c0+1 (in flight during c0 compute)
      a1[0].i = *(const i32x4*)(wB0 + (size_t)(c0 + 1) * 512);
      a1[1].i = *(const i32x4*)(wB1 + (size_t)(c0 + 1) * 512);

      // h dup-pairs for channels c0,c0+1 at this wave's 4 d-tiles (ds_read_b64)
      uint2 hv[4];
#pragma unroll
      for (int t = 0; t < 4; ++t) hv[t] = *(const uint2*)&hD[t * 16 + i][c0];

      // ---- channel c0
#pragma unroll
      for (int t = 0; t < 4; ++t) {
        AB hs, bf;
        hs.u[0] = hv[t].x; hs.u[1] = hv[t].x; hs.u[2] = hv[t].x; hs.u[3] = hv[t].x;
        bf.h = hs.h * xf[t].h;  // 4x v_pk_mul_f16: P[c*32+q*8+j][d]
        acc[t][0] = __builtin_amdgcn_mfma_f32_16x16x32_f16(a0[0].h, bf.h, acc[t][0], 0, 0, 0);
        acc[t][1] = __builtin_amdgcn_mfma_f32_16x16x32_f16(a0[1].h, bf.h, acc[t][1], 0, 0, 0);
      }

      // prefetch W frags for channel c0+2
      int cn = (c0 + 2 < Kch) ? c0 + 2 : 0;
      a0[0].i = *(const i32x4*)(wB0 + (size_t)cn * 512);
      a0[1].i = *(const i32x4*)(wB1 + (size_t)cn * 512);

      // ---- channel c0+1
#pragma unroll
      for (int t = 0; t < 4; ++t) {
        AB hs, bf;
        hs.u[0] = hv[t].y; hs.u[1] = hv[t].y; hs.u[2] = hv[t].y; hs.u[3] = hv[t].y;
        bf.h = hs.h * xf[t].h;
        acc[t][0] = __builtin_amdgcn_mfma_f32_16x16x32_f16(a1[0].h, bf.h, acc[t][0], 0, 0, 0);
        acc[t][1] = __builtin_amdgcn_mfma_f32_16x16x32_f16(a1[1].h, bf.h, acc[t][1], 0, 0, 0);
      }
    }

    // ---- epilogue: bias + ReLU (C layout: o = ot*16 + q*4 + r, d = t*16 + i)
    f32x4 bv[2];
    bv[0] = *(const f32x4*)(bias + (2 * w) * 16 + q * 4);
    bv[1] = *(const f32x4*)(bias + (2 * w + 1) * 16 + q * 4);
#pragma unroll
    for (int t = 0; t < 4; ++t)
#pragma unroll
      for (int g = 0; g < 2; ++g)
#pragma unroll
        for (int r = 0; r < 4; ++r)
          acc[t][g][r] = fmaxf(acc[t][g][r] + bv[g][r], 0.f);

    if (L < 2) {
      __syncthreads();  // all reads of hD done before overwrite
#pragma unroll
      for (int t = 0; t < 4; ++t)
#pragma unroll
        for (int g = 0; g < 2; ++g) {
          uint4 pk;  // dup'd fp16 of the 4 r-values (next layer's h)
          pk.x = dup16(f_to_f16u(acc[t][g][0]));
          pk.y = dup16(f_to_f16u(acc[t][g][1]));
          pk.z = dup16(f_to_f16u(acc[t][g][2]));
          pk.w = dup16(f_to_f16u(acc[t][g][3]));
          // dword off: 132*(16t+i) + (2w+g)*16 + 4q  == 0 mod 4 -> b128 ok
          *(uint4*)&hD[t * 16 + i][(2 * w + g) * 16 + q * 4] = pk;
        }
      __syncthreads();
    }

    // d-sum: in-register over t, then xor-shuffle the 16 i-lanes (within quad group)
#pragma unroll
    for (int g = 0; g < 2; ++g)
#pragma unroll
      for (int r = 0; r < 4; ++r) {
        float s = acc[0][g][r] + acc[1][g][r] + acc[2][g][r] + acc[3][g][r];
        s += __shfl_xor(s, 1);
        s += __shfl_xor(s, 2);
        s += __shfl_xor(s, 4);
        s += __shfl_xor(s, 8);
        if (i == 0)
          out[(size_t)b * 384 + L * 128 + (2 * w + g) * 16 + q * 4 + r] = s;
      }
  }
}

// Pre-pass: W fp32 -> fp16, fragment-major [ot][c][lane][j]: main kernel's
// per-frag load = one contiguous coalesced 1KB global_load_dwordx4 per wave.
__global__ void pack_w(const float* __restrict__ W, uint16_t* __restrict__ Wp,
                       int kshift) {
  const int Kch = 1 << kshift;
  int idx = blockIdx.x * 256 + threadIdx.x;  // ((ot*Kch + c)*4 + q)*16 + i
  int lane = idx & 63;
  int qq = lane >> 4, ii = lane & 15;
  int rest = idx >> 6;
  int c = rest & (Kch - 1);
  int ot = rest >> kshift;
  const float* src = W + (size_t)(ot * 16 + ii) * (Kch * 32) + c * 32 + qq * 8;
  uint32_t o[4];
#pragma unroll
  for (int k = 0; k < 4; ++k)
    o[k] = (uint32_t)f_to_f16u(src[2 * k]) | ((uint32_t)f_to_f16u(src[2 * k + 1]) << 16);
  uint4 val;
  val.x = o[0]; val.y = o[1]; val.z = o[2]; val.w = o[3];
  *(uint4*)(Wp + (size_t)idx * 8) = val;
}

extern "C" void kernel_launch(void* const* d_in, const int* in_sizes, int n_in,
                              void* d_out, int out_size, void* d_ws, size_t ws_size,
                              hipStream_t stream) {
  (void)in_sizes; (void)n_in; (void)out_size; (void)ws_size;
  const float* x  = (const float*)d_in[0];
  const float* W0 = (const float*)d_in[1];
  const float* b0 = (const float*)d_in[2];
  const float* W1 = (const float*)d_in[3];
  const float* b1 = (const float*)d_in[4];
  const float* W2 = (const float*)d_in[5];
  const float* b2 = (const float*)d_in[6];
  uint16_t* wpacked = (uint16_t*)d_ws;  // 2.25 MB of ws used

  hipLaunchKernelGGL(pack_w, dim3(64),  dim3(256), 0, stream, W0, wpacked, 5);
  hipLaunchKernelGGL(pack_w, dim3(256), dim3(256), 0, stream, W1, wpacked + 131072, 7);
  hipLaunchKernelGGL(pack_w, dim3(256), dim3(256), 0, stream, W2, wpacked + 131072 + 524288, 7);
  hipLaunchKernelGGL(cin_main, dim3(1024), dim3(256), 0, stream,
                     x, wpacked, b0, b1, b2, (float*)d_out);
}